// Round 2
// baseline (785.989 us; speedup 1.0000x reference)
//
#include <hip/hip_runtime.h>
#include <stdint.h>

// Problem constants (from reference)
#define BB 2
#define SS 2048
#define DD 1024      // model dim
#define HH 4096      // hidden dim
#define EE 8         // experts
#define NTOK (BB*SS) // 4096 tokens
#define NPAIR (NTOK*2)

// GEMM tiling (m97 structure: 128x128 tile, BK=64, linear LDS, global_load_lds)
#define BM 128
#define BN 128
#define BK 64

typedef float f32x4 __attribute__((ext_vector_type(4)));
typedef __bf16 bf16x8 __attribute__((ext_vector_type(8)));
typedef short s16x4 __attribute__((ext_vector_type(4)));
typedef short s16x8 __attribute__((ext_vector_type(8)));

__device__ __forceinline__ unsigned short f2bf(float f) {
    union { float f; uint32_t u; } v; v.f = f;
    return (unsigned short)((v.u + 0x7FFFu + ((v.u >> 16) & 1u)) >> 16);  // RNE
}

__device__ __forceinline__ void gload16(const void* g, void* l) {
    // width-16 global->LDS DMA; LDS dest = wave-uniform base + lane*16
    __builtin_amdgcn_global_load_lds(
        (const __attribute__((address_space(1))) unsigned int*)g,
        (__attribute__((address_space(3))) unsigned int*)l, 16, 0, 0);
}

// ---------------------------------------------------------------------------
// Kernel 1: gating (f32 exact) + x -> bf16 conversion.
// One wave per token. Builds per-expert lists (tok, pid, wgt) via atomics.
// ---------------------------------------------------------------------------
__global__ __launch_bounds__(256) void gate_kernel(
    const float* __restrict__ x, const float* __restrict__ gw,
    const float* __restrict__ gb,
    int* __restrict__ cnt, int* __restrict__ tok, int* __restrict__ pid,
    float* __restrict__ wgt, unsigned short* __restrict__ xb)
{
    int wave = threadIdx.x >> 6;
    int lane = threadIdx.x & 63;
    int t = blockIdx.x * 4 + wave;
    if (t >= NTOK) return;

    float acc[EE];
#pragma unroll
    for (int e = 0; e < EE; ++e) acc[e] = 0.f;

    const float* xr = x + (size_t)t * DD;
    unsigned short* xo = xb + (size_t)t * DD;
    for (int d = lane; d < DD; d += 64) {
        float xv = xr[d];
        xo[d] = f2bf(xv);
        const float* g = gw + (size_t)d * EE;
#pragma unroll
        for (int e = 0; e < EE; ++e) acc[e] += xv * g[e];
    }
#pragma unroll
    for (int e = 0; e < EE; ++e) {
#pragma unroll
        for (int off = 32; off >= 1; off >>= 1)
            acc[e] += __shfl_xor(acc[e], off);
    }
    if (lane == 0) {
        float lg[EE];
        float m = -1e30f;
#pragma unroll
        for (int e = 0; e < EE; ++e) { lg[e] = acc[e] + gb[e]; m = fmaxf(m, lg[e]); }
        float s = 0.f;
#pragma unroll
        for (int e = 0; e < EE; ++e) { lg[e] = expf(lg[e] - m); s += lg[e]; }
        float inv = 1.f / s;
        int e0 = 0; float v0 = lg[0];
#pragma unroll
        for (int e = 1; e < EE; ++e) if (lg[e] > v0) { v0 = lg[e]; e0 = e; }
        int e1 = -1; float v1 = -1.f;
#pragma unroll
        for (int e = 0; e < EE; ++e) if (e != e0 && lg[e] > v1) { v1 = lg[e]; e1 = e; }

        int p0 = atomicAdd(&cnt[e0], 1);
        tok[e0 * NTOK + p0] = t; pid[e0 * NTOK + p0] = 2 * t;     wgt[e0 * NTOK + p0] = v0 * inv;
        int p1 = atomicAdd(&cnt[e1], 1);
        tok[e1 * NTOK + p1] = t; pid[e1 * NTOK + p1] = 2 * t + 1; wgt[e1 * NTOK + p1] = v1 * inv;
    }
}

// ---------------------------------------------------------------------------
// Kernel 2: tiled transpose + f32->bf16 convert.  in [E][R][C] f32 -> out [E][C][R] bf16.
// Fully coalesced both sides; LDS 64x65 f32 pad kills bank conflicts.
// ---------------------------------------------------------------------------
__global__ __launch_bounds__(256) void transpose_cvt_kernel(
    const float* __restrict__ in, unsigned short* __restrict__ out, int R, int C)
{
    __shared__ float t[64][65];
    const int e = blockIdx.z;
    const int r0 = blockIdx.y * 64;
    const int c0 = blockIdx.x * 64;
    const float* src = in + (size_t)e * R * C;
    unsigned short* dst = out + (size_t)e * R * C;
    const int tid = threadIdx.x;
    const int lr = tid >> 4;         // 0..15
    const int lc = (tid & 15) * 4;   // 0..60
#pragma unroll
    for (int p = 0; p < 4; ++p) {
        int row = p * 16 + lr;
        const float4 v = *(const float4*)(src + (size_t)(r0 + row) * C + c0 + lc);
        t[row][lc]     = v.x; t[row][lc + 1] = v.y;
        t[row][lc + 2] = v.z; t[row][lc + 3] = v.w;
    }
    __syncthreads();
#pragma unroll
    for (int p = 0; p < 4; ++p) {
        int crow = p * 16 + lr;
        s16x4 b;
#pragma unroll
        for (int j = 0; j < 4; ++j) b[j] = (short)f2bf(t[lc + j][crow]);
        *(s16x4*)(dst + (size_t)(c0 + crow) * R + r0 + lc) = b;
    }
}

// ---------------------------------------------------------------------------
// Kernel 3: pass A — hidden[pair] = relu(xb[tok] @ w1t^T + b1[e]), bf16 out.
// A: gathered token rows (global_load_lds, per-lane src addr).
// B: w1t [E][H][D] rows (contraction dim D contiguous).
// ---------------------------------------------------------------------------
__global__ __launch_bounds__(256) void ffn1_kernel(
    const unsigned short* __restrict__ xb, const unsigned short* __restrict__ w1t,
    const float* __restrict__ b1,
    const int* __restrict__ cnt, const int* __restrict__ tok,
    const int* __restrict__ pid,
    unsigned short* __restrict__ hid)
{
    const int e = blockIdx.z;
    const int mt = blockIdx.y;
    const int nt = blockIdx.x;
    const int Me = cnt[e];
    if (mt * BM >= Me) return;

    __shared__ unsigned short As[BM][BK];   // linear: global_load_lds dest
    __shared__ unsigned short Bs[BN][BK];
    __shared__ int tl[BM];

    const int tid = threadIdx.x;
    if (tid < BM) {
        int p = mt * BM + tid;
        tl[tid] = (p < Me) ? tok[e * NTOK + p] : 0;
    }
    __syncthreads();

    const int lane = tid & 63;
    const int wv = tid >> 6;
    const int wr = wv >> 1, wc = wv & 1;

    // staging geometry: wave wv owns LDS rows [wv*32, wv*32+32), 4 issues of 8 rows
    const int srow = lane >> 3;        // 0..7 row within 8-row group
    const int scol = (lane & 7) * 8;   // element offset within row (16B chunks)

    const unsigned short* aSrc[4];
#pragma unroll
    for (int i = 0; i < 4; ++i)
        aSrc[i] = xb + (size_t)tl[wv * 32 + i * 8 + srow] * DD + scol;
    const unsigned short* bE = w1t + (size_t)e * DD * HH;  // [H][D]
    const unsigned short* bSrc[4];
#pragma unroll
    for (int i = 0; i < 4; ++i)
        bSrc[i] = bE + (size_t)(nt * BN + wv * 32 + i * 8 + srow) * DD + scol;

    f32x4 acc[4][4];
#pragma unroll
    for (int m = 0; m < 4; ++m)
#pragma unroll
        for (int n = 0; n < 4; ++n)
#pragma unroll
            for (int q = 0; q < 4; ++q) acc[m][n][q] = 0.f;

    for (int k0 = 0; k0 < DD; k0 += BK) {
#pragma unroll
        for (int i = 0; i < 4; ++i)
            gload16(aSrc[i] + k0, &As[wv * 32 + i * 8][0]);
#pragma unroll
        for (int i = 0; i < 4; ++i)
            gload16(bSrc[i] + k0, &Bs[wv * 32 + i * 8][0]);
        asm volatile("s_waitcnt vmcnt(0)" ::: "memory");
        __syncthreads();
#pragma unroll
        for (int ks = 0; ks < BK; ks += 32) {
            bf16x8 af[4], bfr[4];
            const int kb = ks + (lane >> 4) * 8;
#pragma unroll
            for (int m = 0; m < 4; ++m)
                af[m] = *(const bf16x8*)&As[wr * 64 + m * 16 + (lane & 15)][kb];
#pragma unroll
            for (int n = 0; n < 4; ++n)
                bfr[n] = *(const bf16x8*)&Bs[wc * 64 + n * 16 + (lane & 15)][kb];
#pragma unroll
            for (int m = 0; m < 4; ++m)
#pragma unroll
                for (int n = 0; n < 4; ++n)
                    acc[m][n] = __builtin_amdgcn_mfma_f32_16x16x32_bf16(af[m], bfr[n], acc[m][n], 0, 0, 0);
        }
        __syncthreads();
    }

    const int nbase = nt * BN;
#pragma unroll
    for (int m = 0; m < 4; ++m) {
#pragma unroll
        for (int q = 0; q < 4; ++q) {
            int rloc = wr * 64 + m * 16 + (lane >> 4) * 4 + q;
            int p = mt * BM + rloc;
            if (p < Me) {
                int pp = pid[e * NTOK + p];
                unsigned short* dst = hid + (size_t)pp * HH;
#pragma unroll
                for (int n = 0; n < 4; ++n) {
                    int ng = nbase + wc * 64 + n * 16 + (lane & 15);
                    float h = acc[m][n][q] + b1[(size_t)e * HH + ng];
                    dst[ng] = f2bf(fmaxf(h, 0.f));
                }
            }
        }
    }
}

// ---------------------------------------------------------------------------
// Kernel 4: pass B — out[tok] += wgt * (hid[pair] @ w2t^T + b2[e]).
// A: gathered hid rows (bf16 already). B: w2t [E][D][H] (contraction H contiguous).
// ---------------------------------------------------------------------------
__global__ __launch_bounds__(256) void ffn2_kernel(
    const unsigned short* __restrict__ hid, const unsigned short* __restrict__ w2t,
    const float* __restrict__ b2,
    const int* __restrict__ cnt, const int* __restrict__ tok,
    const int* __restrict__ pid, const float* __restrict__ wgt,
    float* __restrict__ out)
{
    const int e = blockIdx.z;
    const int mt = blockIdx.y;
    const int nt = blockIdx.x;
    const int Me = cnt[e];
    if (mt * BM >= Me) return;

    __shared__ unsigned short As[BM][BK];
    __shared__ unsigned short Bs[BN][BK];
    __shared__ int pl[BM];

    const int tid = threadIdx.x;
    if (tid < BM) {
        int p = mt * BM + tid;
        pl[tid] = (p < Me) ? pid[e * NTOK + p] : 0;
    }
    __syncthreads();

    const int lane = tid & 63;
    const int wv = tid >> 6;
    const int wr = wv >> 1, wc = wv & 1;

    const int srow = lane >> 3;
    const int scol = (lane & 7) * 8;

    const unsigned short* aSrc[4];
#pragma unroll
    for (int i = 0; i < 4; ++i)
        aSrc[i] = hid + (size_t)pl[wv * 32 + i * 8 + srow] * HH + scol;
    const unsigned short* bE = w2t + (size_t)e * DD * HH;  // [D][H]
    const unsigned short* bSrc[4];
#pragma unroll
    for (int i = 0; i < 4; ++i)
        bSrc[i] = bE + (size_t)(nt * BN + wv * 32 + i * 8 + srow) * HH + scol;

    f32x4 acc[4][4];
#pragma unroll
    for (int m = 0; m < 4; ++m)
#pragma unroll
        for (int n = 0; n < 4; ++n)
#pragma unroll
            for (int q = 0; q < 4; ++q) acc[m][n][q] = 0.f;

    for (int k0 = 0; k0 < HH; k0 += BK) {
#pragma unroll
        for (int i = 0; i < 4; ++i)
            gload16(aSrc[i] + k0, &As[wv * 32 + i * 8][0]);
#pragma unroll
        for (int i = 0; i < 4; ++i)
            gload16(bSrc[i] + k0, &Bs[wv * 32 + i * 8][0]);
        asm volatile("s_waitcnt vmcnt(0)" ::: "memory");
        __syncthreads();
#pragma unroll
        for (int ks = 0; ks < BK; ks += 32) {
            bf16x8 af[4], bfr[4];
            const int kb = ks + (lane >> 4) * 8;
#pragma unroll
            for (int m = 0; m < 4; ++m)
                af[m] = *(const bf16x8*)&As[wr * 64 + m * 16 + (lane & 15)][kb];
#pragma unroll
            for (int n = 0; n < 4; ++n)
                bfr[n] = *(const bf16x8*)&Bs[wc * 64 + n * 16 + (lane & 15)][kb];
#pragma unroll
            for (int m = 0; m < 4; ++m)
#pragma unroll
                for (int n = 0; n < 4; ++n)
                    acc[m][n] = __builtin_amdgcn_mfma_f32_16x16x32_bf16(af[m], bfr[n], acc[m][n], 0, 0, 0);
        }
        __syncthreads();
    }

    const int nbase = nt * BN;
#pragma unroll
    for (int m = 0; m < 4; ++m) {
#pragma unroll
        for (int q = 0; q < 4; ++q) {
            int rloc = wr * 64 + m * 16 + (lane >> 4) * 4 + q;
            int p = mt * BM + rloc;
            if (p < Me) {
                int t = tok[e * NTOK + p];
                float wvv = wgt[e * NTOK + p];
                float* dst = out + (size_t)t * DD;
#pragma unroll
                for (int n = 0; n < 4; ++n) {
                    int ng = nbase + wc * 64 + n * 16 + (lane & 15);
                    float val = wvv * (acc[m][n][q] + b2[(size_t)e * DD + ng]);
                    atomicAdd(&dst[ng], val);
                }
            }
        }
    }
}

// ---------------------------------------------------------------------------
// Workspace layout (bytes, 256-aligned):
//   cnt   @ 0          256
//   tok   @ 256        128K   int[E][NTOK]
//   pid   @ +128K      128K
//   wgt   @ +128K      128K
//   xb    @ +128K      8M     bf16[NTOK][DD]
//   hid   @ +8M        64M    bf16[NPAIR][HH]
//   wt    @ +64M       64M    bf16 weights (w1t during ffn1, then reused for w2t)
// Total ~136.8 MB.
// ---------------------------------------------------------------------------
extern "C" void kernel_launch(void* const* d_in, const int* in_sizes, int n_in,
                              void* d_out, int out_size, void* d_ws, size_t ws_size,
                              hipStream_t stream) {
    const float* x   = (const float*)d_in[0];
    const float* gw  = (const float*)d_in[1];
    const float* gb  = (const float*)d_in[2];
    const float* w1  = (const float*)d_in[3];
    const float* b1  = (const float*)d_in[4];
    const float* w2  = (const float*)d_in[5];
    const float* b2  = (const float*)d_in[6];
    float* out = (float*)d_out;

    char* ws = (char*)d_ws;
    size_t off = 0;
    int*   cnt = (int*)(ws + off);   off += 256;
    int*   tok = (int*)(ws + off);   off += (size_t)4 * EE * NTOK;
    int*   pid = (int*)(ws + off);   off += (size_t)4 * EE * NTOK;
    float* wgt = (float*)(ws + off); off += (size_t)4 * EE * NTOK;
    unsigned short* xb  = (unsigned short*)(ws + off); off += (size_t)NTOK * DD * 2;
    unsigned short* hid = (unsigned short*)(ws + off); off += (size_t)NPAIR * HH * 2;
    unsigned short* wt  = (unsigned short*)(ws + off); off += (size_t)EE * DD * HH * 2;

    hipMemsetAsync(cnt, 0, 256, stream);
    hipMemsetAsync(out, 0, (size_t)out_size * sizeof(float), stream);

    gate_kernel<<<NTOK / 4, 256, 0, stream>>>(x, gw, gb, cnt, tok, pid, wgt, xb);

    // w1 [E][D][H] -> wt = w1t [E][H][D]
    transpose_cvt_kernel<<<dim3(HH / 64, DD / 64, EE), 256, 0, stream>>>(w1, wt, DD, HH);
    ffn1_kernel<<<dim3(HH / BN, NTOK / BM, EE), 256, 0, stream>>>(
        xb, wt, b1, cnt, tok, pid, hid);

    // w2 [E][H][D] -> wt = w2t [E][D][H]  (reuses the same buffer; stream-ordered)
    transpose_cvt_kernel<<<dim3(DD / 64, HH / 64, EE), 256, 0, stream>>>(w2, wt, HH, DD);
    ffn2_kernel<<<dim3(DD / BN, NTOK / BM, EE), 256, 0, stream>>>(
        hid, wt, b2, cnt, tok, pid, wgt, out);
}

// Round 4
// 764.229 us; speedup vs baseline: 1.0285x; 1.0285x over previous
//
#include <hip/hip_runtime.h>
#include <stdint.h>

// Problem constants (from reference)
#define BB 2
#define SS 2048
#define DD 1024      // model dim
#define HH 4096      // hidden dim
#define EE 8         // experts
#define NTOK (BB*SS) // 4096 tokens
#define NPAIR (NTOK*2)

// GEMM tiling (128x128 tile, BK=64, double-buffered LDS, global_load_lds)
#define BM 128
#define BN 128
#define BK 64
#define KSPLIT 4     // split-K factor for ffn2

typedef float f32x4 __attribute__((ext_vector_type(4)));
typedef __bf16 bf16x8 __attribute__((ext_vector_type(8)));
typedef short s16x4 __attribute__((ext_vector_type(4)));
typedef short s16x8 __attribute__((ext_vector_type(8)));

__device__ __forceinline__ unsigned short f2bf(float f) {
    union { float f; uint32_t u; } v; v.f = f;
    return (unsigned short)((v.u + 0x7FFFu + ((v.u >> 16) & 1u)) >> 16);  // RNE
}

__device__ __forceinline__ void gload16(const void* g, void* l) {
    // width-16 global->LDS DMA; LDS dest = wave-uniform base + lane*16
    __builtin_amdgcn_global_load_lds(
        (const __attribute__((address_space(1))) unsigned int*)g,
        (__attribute__((address_space(3))) unsigned int*)l, 16, 0, 0);
}

// ---------------------------------------------------------------------------
// Kernel 1: gating (f32 exact) + x -> bf16 conversion.
// ---------------------------------------------------------------------------
__global__ __launch_bounds__(256) void gate_kernel(
    const float* __restrict__ x, const float* __restrict__ gw,
    const float* __restrict__ gb,
    int* __restrict__ cnt, int* __restrict__ tok, int* __restrict__ pid,
    float* __restrict__ wgt, unsigned short* __restrict__ xb)
{
    int wave = threadIdx.x >> 6;
    int lane = threadIdx.x & 63;
    int t = blockIdx.x * 4 + wave;
    if (t >= NTOK) return;

    float acc[EE];
#pragma unroll
    for (int e = 0; e < EE; ++e) acc[e] = 0.f;

    const float* xr = x + (size_t)t * DD;
    unsigned short* xo = xb + (size_t)t * DD;
    for (int d = lane; d < DD; d += 64) {
        float xv = xr[d];
        xo[d] = f2bf(xv);
        const float* g = gw + (size_t)d * EE;
#pragma unroll
        for (int e = 0; e < EE; ++e) acc[e] += xv * g[e];
    }
#pragma unroll
    for (int e = 0; e < EE; ++e) {
#pragma unroll
        for (int off = 32; off >= 1; off >>= 1)
            acc[e] += __shfl_xor(acc[e], off);
    }
    if (lane == 0) {
        float lg[EE];
        float m = -1e30f;
#pragma unroll
        for (int e = 0; e < EE; ++e) { lg[e] = acc[e] + gb[e]; m = fmaxf(m, lg[e]); }
        float s = 0.f;
#pragma unroll
        for (int e = 0; e < EE; ++e) { lg[e] = expf(lg[e] - m); s += lg[e]; }
        float inv = 1.f / s;
        int e0 = 0; float v0 = lg[0];
#pragma unroll
        for (int e = 1; e < EE; ++e) if (lg[e] > v0) { v0 = lg[e]; e0 = e; }
        int e1 = -1; float v1 = -1.f;
#pragma unroll
        for (int e = 0; e < EE; ++e) if (e != e0 && lg[e] > v1) { v1 = lg[e]; e1 = e; }

        int p0 = atomicAdd(&cnt[e0], 1);
        tok[e0 * NTOK + p0] = t; pid[e0 * NTOK + p0] = 2 * t;     wgt[e0 * NTOK + p0] = v0 * inv;
        int p1 = atomicAdd(&cnt[e1], 1);
        tok[e1 * NTOK + p1] = t; pid[e1 * NTOK + p1] = 2 * t + 1; wgt[e1 * NTOK + p1] = v1 * inv;
    }
}

// ---------------------------------------------------------------------------
// Kernel 2: tiled transpose + f32->bf16.  in [E][R][C] f32 -> out [E][C][R] bf16.
// ---------------------------------------------------------------------------
__global__ __launch_bounds__(256) void transpose_cvt_kernel(
    const float* __restrict__ in, unsigned short* __restrict__ out, int R, int C)
{
    __shared__ float t[64][65];
    const int e = blockIdx.z;
    const int r0 = blockIdx.y * 64;
    const int c0 = blockIdx.x * 64;
    const float* src = in + (size_t)e * R * C;
    unsigned short* dst = out + (size_t)e * R * C;
    const int tid = threadIdx.x;
    const int lr = tid >> 4;
    const int lc = (tid & 15) * 4;
#pragma unroll
    for (int p = 0; p < 4; ++p) {
        int row = p * 16 + lr;
        const float4 v = *(const float4*)(src + (size_t)(r0 + row) * C + c0 + lc);
        t[row][lc]     = v.x; t[row][lc + 1] = v.y;
        t[row][lc + 2] = v.z; t[row][lc + 3] = v.w;
    }
    __syncthreads();
#pragma unroll
    for (int p = 0; p < 4; ++p) {
        int crow = p * 16 + lr;
        s16x4 b;
#pragma unroll
        for (int j = 0; j < 4; ++j) b[j] = (short)f2bf(t[lc + j][crow]);
        *(s16x4*)(dst + (size_t)(c0 + crow) * R + r0 + lc) = b;
    }
}

// ---------------------------------------------------------------------------
// Shared GEMM tile machinery (swizzled LDS, 2-phase double buffer).
// LDS layout: As[buf][128][64] bf16 (linear dest for global_load_lds).
// Swizzle (rule #21, both-sides-or-neither): LDS[row][chunk c] holds global
// chunk c ^ (row&7)  (16B chunks). Staging lane loads global chunk
// (lane&7)^(lane>>3); reader XORs chunk with row&7. 16-way conflict -> 2-way.
// ---------------------------------------------------------------------------

// Per-wave fragment compute for one buffered tile: 32 MFMA.
__device__ __forceinline__ void tile_mfma(
    const unsigned short (*As)[BK], const unsigned short (*Bs)[BK],
    int lane, int wr, int wc, f32x4 acc[4][4])
{
#pragma unroll
    for (int ks = 0; ks < BK; ks += 32) {
        bf16x8 af[4], bfr[4];
        const int g = (ks >> 3) + (lane >> 4);   // global 16B-chunk index
#pragma unroll
        for (int m = 0; m < 4; ++m) {
            int ar = wr * 64 + m * 16 + (lane & 15);
            af[m] = *(const bf16x8*)&As[ar][(g ^ (ar & 7)) * 8];
        }
#pragma unroll
        for (int n = 0; n < 4; ++n) {
            int br = wc * 64 + n * 16 + (lane & 15);
            bfr[n] = *(const bf16x8*)&Bs[br][(g ^ (br & 7)) * 8];
        }
#pragma unroll
        for (int m = 0; m < 4; ++m)
#pragma unroll
            for (int n = 0; n < 4; ++n)
                acc[m][n] = __builtin_amdgcn_mfma_f32_16x16x32_bf16(af[m], bfr[n], acc[m][n], 0, 0, 0);
    }
}

// ---------------------------------------------------------------------------
// Kernel 3: pass A — hidden[pair] = relu(xb[tok] @ w1t^T + b1[e]), bf16 out.
// ---------------------------------------------------------------------------
__global__ __launch_bounds__(256) void ffn1_kernel(
    const unsigned short* __restrict__ xb, const unsigned short* __restrict__ w1t,
    const float* __restrict__ b1,
    const int* __restrict__ cnt, const int* __restrict__ tok,
    const int* __restrict__ pid,
    unsigned short* __restrict__ hid)
{
    const int e = blockIdx.z;
    const int mt = blockIdx.y;
    const int nt = blockIdx.x;
    const int Me = cnt[e];
    if (mt * BM >= Me) return;

    __shared__ unsigned short As[2][BM][BK];
    __shared__ unsigned short Bs[2][BN][BK];
    __shared__ int tl[BM];

    const int tid = threadIdx.x;
    if (tid < BM) {
        int p = mt * BM + tid;
        tl[tid] = (p < Me) ? tok[e * NTOK + p] : 0;
    }
    __syncthreads();

    const int lane = tid & 63;
    const int wv = tid >> 6;
    const int wr = wv >> 1, wc = wv & 1;

    // staging geometry (per wave: 32 LDS rows, 4 gload16 issues of 8 rows)
    const int srow = lane >> 3;                         // row within 8-row group
    const int scol = (((lane & 7) ^ srow)) * 8;          // swizzled 16B chunk

    const unsigned short* aSrc[4];
#pragma unroll
    for (int i = 0; i < 4; ++i)
        aSrc[i] = xb + (size_t)tl[wv * 32 + i * 8 + srow] * DD + scol;
    const unsigned short* bE = w1t + (size_t)e * DD * HH;  // [H][D]
    const unsigned short* bSrc[4];
#pragma unroll
    for (int i = 0; i < 4; ++i)
        bSrc[i] = bE + (size_t)(nt * BN + wv * 32 + i * 8 + srow) * DD + scol;

    f32x4 acc[4][4];
#pragma unroll
    for (int m = 0; m < 4; ++m)
#pragma unroll
        for (int n = 0; n < 4; ++n)
#pragma unroll
            for (int q = 0; q < 4; ++q) acc[m][n][q] = 0.f;

    const int nk = DD / BK;
    // prologue
#pragma unroll
    for (int i = 0; i < 4; ++i) gload16(aSrc[i], &As[0][wv * 32 + i * 8][0]);
#pragma unroll
    for (int i = 0; i < 4; ++i) gload16(bSrc[i], &Bs[0][wv * 32 + i * 8][0]);
    __syncthreads();   // vmcnt(0) drain + barrier

    int cur = 0;
    for (int t = 0; t < nk; ++t) {
        if (t + 1 < nk) {
            const int k0 = (t + 1) * BK;
#pragma unroll
            for (int i = 0; i < 4; ++i) gload16(aSrc[i] + k0, &As[cur ^ 1][wv * 32 + i * 8][0]);
#pragma unroll
            for (int i = 0; i < 4; ++i) gload16(bSrc[i] + k0, &Bs[cur ^ 1][wv * 32 + i * 8][0]);
        }
        tile_mfma(As[cur], Bs[cur], lane, wr, wc, acc);
        __syncthreads();   // implicit vmcnt(0): next buffer ready
        cur ^= 1;
    }

    const int nbase = nt * BN;
#pragma unroll
    for (int m = 0; m < 4; ++m) {
#pragma unroll
        for (int q = 0; q < 4; ++q) {
            int rloc = wr * 64 + m * 16 + (lane >> 4) * 4 + q;
            int p = mt * BM + rloc;
            if (p < Me) {
                int pp = pid[e * NTOK + p];
                unsigned short* dst = hid + (size_t)pp * HH;
#pragma unroll
                for (int n = 0; n < 4; ++n) {
                    int ng = nbase + wc * 64 + n * 16 + (lane & 15);
                    float h = acc[m][n][q] + b1[(size_t)e * HH + ng];
                    dst[ng] = f2bf(fmaxf(h, 0.f));
                }
            }
        }
    }
}

// ---------------------------------------------------------------------------
// Kernel 4: pass B — out[tok] += wgt * (hid[pair] @ w2t^T + b2[e]).
// Split-K: gridDim.z = EE*KSPLIT; each chunk covers HH/KSPLIT of K.
// ---------------------------------------------------------------------------
__global__ __launch_bounds__(256) void ffn2_kernel(
    const unsigned short* __restrict__ hid, const unsigned short* __restrict__ w2t,
    const float* __restrict__ b2,
    const int* __restrict__ cnt, const int* __restrict__ tok,
    const int* __restrict__ pid, const float* __restrict__ wgt,
    float* __restrict__ out)
{
    const int e  = blockIdx.z >> 2;
    const int kc = blockIdx.z & (KSPLIT - 1);
    const int mt = blockIdx.y;
    const int nt = blockIdx.x;
    const int Me = cnt[e];
    if (mt * BM >= Me) return;

    __shared__ unsigned short As[2][BM][BK];
    __shared__ unsigned short Bs[2][BN][BK];
    __shared__ int pl[BM];

    const int tid = threadIdx.x;
    if (tid < BM) {
        int p = mt * BM + tid;
        pl[tid] = (p < Me) ? pid[e * NTOK + p] : 0;
    }
    __syncthreads();

    const int lane = tid & 63;
    const int wv = tid >> 6;
    const int wr = wv >> 1, wc = wv & 1;

    const int srow = lane >> 3;
    const int scol = (((lane & 7) ^ srow)) * 8;
    const int kbase = kc * (HH / KSPLIT);

    const unsigned short* aSrc[4];
#pragma unroll
    for (int i = 0; i < 4; ++i)
        aSrc[i] = hid + (size_t)pl[wv * 32 + i * 8 + srow] * HH + kbase + scol;
    const unsigned short* bE = w2t + (size_t)e * DD * HH;  // [D][H]
    const unsigned short* bSrc[4];
#pragma unroll
    for (int i = 0; i < 4; ++i)
        bSrc[i] = bE + (size_t)(nt * BN + wv * 32 + i * 8 + srow) * HH + kbase + scol;

    f32x4 acc[4][4];
#pragma unroll
    for (int m = 0; m < 4; ++m)
#pragma unroll
        for (int n = 0; n < 4; ++n)
#pragma unroll
            for (int q = 0; q < 4; ++q) acc[m][n][q] = 0.f;

    const int nk = (HH / KSPLIT) / BK;   // 16
#pragma unroll
    for (int i = 0; i < 4; ++i) gload16(aSrc[i], &As[0][wv * 32 + i * 8][0]);
#pragma unroll
    for (int i = 0; i < 4; ++i) gload16(bSrc[i], &Bs[0][wv * 32 + i * 8][0]);
    __syncthreads();

    int cur = 0;
    for (int t = 0; t < nk; ++t) {
        if (t + 1 < nk) {
            const int k0 = (t + 1) * BK;
#pragma unroll
            for (int i = 0; i < 4; ++i) gload16(aSrc[i] + k0, &As[cur ^ 1][wv * 32 + i * 8][0]);
#pragma unroll
            for (int i = 0; i < 4; ++i) gload16(bSrc[i] + k0, &Bs[cur ^ 1][wv * 32 + i * 8][0]);
        }
        tile_mfma(As[cur], Bs[cur], lane, wr, wc, acc);
        __syncthreads();
        cur ^= 1;
    }

    const int nbase = nt * BN;
#pragma unroll
    for (int m = 0; m < 4; ++m) {
#pragma unroll
        for (int q = 0; q < 4; ++q) {
            int rloc = wr * 64 + m * 16 + (lane >> 4) * 4 + q;
            int p = mt * BM + rloc;
            if (p < Me) {
                int t = tok[e * NTOK + p];
                float wvv = wgt[e * NTOK + p];
                float* dst = out + (size_t)t * DD;
#pragma unroll
                for (int n = 0; n < 4; ++n) {
                    int ng = nbase + wc * 64 + n * 16 + (lane & 15);
                    float val = acc[m][n][q];
                    if (kc == 0) val += b2[(size_t)e * DD + ng];
                    atomicAdd(&dst[ng], wvv * val);
                }
            }
        }
    }
}

// ---------------------------------------------------------------------------
// Workspace layout: cnt(256B) | tok | pid | wgt (128K each) | xb 8M | hid 64M
// | wt 64M (w1t during ffn1, reused for w2t). Total ~136.8 MB.
// ---------------------------------------------------------------------------
extern "C" void kernel_launch(void* const* d_in, const int* in_sizes, int n_in,
                              void* d_out, int out_size, void* d_ws, size_t ws_size,
                              hipStream_t stream) {
    const float* x   = (const float*)d_in[0];
    const float* gw  = (const float*)d_in[1];
    const float* gb  = (const float*)d_in[2];
    const float* w1  = (const float*)d_in[3];
    const float* b1  = (const float*)d_in[4];
    const float* w2  = (const float*)d_in[5];
    const float* b2  = (const float*)d_in[6];
    float* out = (float*)d_out;

    char* ws = (char*)d_ws;
    size_t off = 0;
    int*   cnt = (int*)(ws + off);   off += 256;
    int*   tok = (int*)(ws + off);   off += (size_t)4 * EE * NTOK;
    int*   pid = (int*)(ws + off);   off += (size_t)4 * EE * NTOK;
    float* wgt = (float*)(ws + off); off += (size_t)4 * EE * NTOK;
    unsigned short* xb  = (unsigned short*)(ws + off); off += (size_t)NTOK * DD * 2;
    unsigned short* hid = (unsigned short*)(ws + off); off += (size_t)NPAIR * HH * 2;
    unsigned short* wt  = (unsigned short*)(ws + off); off += (size_t)EE * DD * HH * 2;

    hipMemsetAsync(cnt, 0, 256, stream);
    hipMemsetAsync(out, 0, (size_t)out_size * sizeof(float), stream);

    gate_kernel<<<NTOK / 4, 256, 0, stream>>>(x, gw, gb, cnt, tok, pid, wgt, xb);

    // w1 [E][D][H] -> wt = w1t [E][H][D]
    transpose_cvt_kernel<<<dim3(HH / 64, DD / 64, EE), 256, 0, stream>>>(w1, wt, DD, HH);
    ffn1_kernel<<<dim3(HH / BN, NTOK / BM, EE), 256, 0, stream>>>(
        xb, wt, b1, cnt, tok, pid, hid);

    // w2 [E][H][D] -> wt = w2t [E][D][H]
    transpose_cvt_kernel<<<dim3(DD / 64, HH / 64, EE), 256, 0, stream>>>(w2, wt, HH, DD);
    ffn2_kernel<<<dim3(DD / BN, NTOK / BM, EE * KSPLIT), 256, 0, stream>>>(
        hid, wt, b2, cnt, tok, pid, wgt, out);
}

// Round 7
// 645.939 us; speedup vs baseline: 1.2168x; 1.1831x over previous
//
#include <hip/hip_runtime.h>
#include <stdint.h>

// Problem constants (from reference)
#define BB 2
#define SS 2048
#define DD 1024      // model dim
#define HH 4096      // hidden dim
#define EE 8         // experts
#define NTOK (BB*SS) // 4096 tokens
#define NPAIR (NTOK*2)

// GEMM tiling: single-buffered LDS (m97 structure), high block residency.
#define BM 128       // ffn1 M-tile
#define BM2 64       // ffn2 M-tile (N only 8 tiles wide -> need more blocks)
#define BN 128
#define BK 64
#define KSPLIT 2     // ffn2 K-split (K=4096 -> 2 chunks of 2048)

typedef float f32x4 __attribute__((ext_vector_type(4)));
typedef __bf16 bf16x8 __attribute__((ext_vector_type(8)));
typedef short s16x4 __attribute__((ext_vector_type(4)));
typedef short s16x8 __attribute__((ext_vector_type(8)));

__device__ __forceinline__ unsigned short f2bf(float f) {
    union { float f; uint32_t u; } v; v.f = f;
    return (unsigned short)((v.u + 0x7FFFu + ((v.u >> 16) & 1u)) >> 16);  // RNE
}
__device__ __forceinline__ float bf2f(unsigned short u) {
    union { uint32_t u; float f; } v; v.u = ((uint32_t)u) << 16; return v.f;
}

__device__ __forceinline__ void gload16(const void* g, void* l) {
    __builtin_amdgcn_global_load_lds(
        (const __attribute__((address_space(1))) unsigned int*)g,
        (__attribute__((address_space(3))) unsigned int*)l, 16, 0, 0);
}

// ---------------------------------------------------------------------------
// Kernel 1: gating (f32 exact) + x -> bf16. Emits per-expert lists (tok, pid)
// and token-major (etok, wtok) for the combine kernel.
// ---------------------------------------------------------------------------
__global__ __launch_bounds__(256) void gate_kernel(
    const float* __restrict__ x, const float* __restrict__ gw,
    const float* __restrict__ gb,
    int* __restrict__ cnt, int* __restrict__ tok, int* __restrict__ pid,
    int* __restrict__ etok, float* __restrict__ wtok,
    unsigned short* __restrict__ xb)
{
    int wave = threadIdx.x >> 6;
    int lane = threadIdx.x & 63;
    int t = blockIdx.x * 4 + wave;
    if (t >= NTOK) return;

    float acc[EE];
#pragma unroll
    for (int e = 0; e < EE; ++e) acc[e] = 0.f;

    const float* xr = x + (size_t)t * DD;
    unsigned short* xo = xb + (size_t)t * DD;
    for (int d = lane; d < DD; d += 64) {
        float xv = xr[d];
        xo[d] = f2bf(xv);
        const float* g = gw + (size_t)d * EE;
#pragma unroll
        for (int e = 0; e < EE; ++e) acc[e] += xv * g[e];
    }
#pragma unroll
    for (int e = 0; e < EE; ++e) {
#pragma unroll
        for (int off = 32; off >= 1; off >>= 1)
            acc[e] += __shfl_xor(acc[e], off);
    }
    if (lane == 0) {
        float lg[EE];
        float m = -1e30f;
#pragma unroll
        for (int e = 0; e < EE; ++e) { lg[e] = acc[e] + gb[e]; m = fmaxf(m, lg[e]); }
        float s = 0.f;
#pragma unroll
        for (int e = 0; e < EE; ++e) { lg[e] = expf(lg[e] - m); s += lg[e]; }
        float inv = 1.f / s;
        int e0 = 0; float v0 = lg[0];
#pragma unroll
        for (int e = 1; e < EE; ++e) if (lg[e] > v0) { v0 = lg[e]; e0 = e; }
        int e1 = -1; float v1 = -1.f;
#pragma unroll
        for (int e = 0; e < EE; ++e) if (e != e0 && lg[e] > v1) { v1 = lg[e]; e1 = e; }

        int p0 = atomicAdd(&cnt[e0], 1);
        tok[e0 * NTOK + p0] = t; pid[e0 * NTOK + p0] = 2 * t;
        int p1 = atomicAdd(&cnt[e1], 1);
        tok[e1 * NTOK + p1] = t; pid[e1 * NTOK + p1] = 2 * t + 1;
        etok[2 * t] = e0;     wtok[2 * t] = v0 * inv;
        etok[2 * t + 1] = e1; wtok[2 * t + 1] = v1 * inv;
    }
}

// ---------------------------------------------------------------------------
// Kernel 2: tiled transpose + f32->bf16.  in [4][R][C] f32 -> out [4][C][R] bf16.
// (caller pre-offsets `in` by the expert-half; z covers 4 local experts)
// ---------------------------------------------------------------------------
__global__ __launch_bounds__(256) void transpose_cvt_kernel(
    const float* __restrict__ in, unsigned short* __restrict__ out, int R, int C)
{
    __shared__ float t[64][65];
    const int e = blockIdx.z;
    const int r0 = blockIdx.y * 64;
    const int c0 = blockIdx.x * 64;
    const float* src = in + (size_t)e * R * C;
    unsigned short* dst = out + (size_t)e * R * C;
    const int tid = threadIdx.x;
    const int lr = tid >> 4;
    const int lc = (tid & 15) * 4;
#pragma unroll
    for (int p = 0; p < 4; ++p) {
        int row = p * 16 + lr;
        const float4 v = *(const float4*)(src + (size_t)(r0 + row) * C + c0 + lc);
        t[row][lc]     = v.x; t[row][lc + 1] = v.y;
        t[row][lc + 2] = v.z; t[row][lc + 3] = v.w;
    }
    __syncthreads();
#pragma unroll
    for (int p = 0; p < 4; ++p) {
        int crow = p * 16 + lr;
        s16x4 b;
#pragma unroll
        for (int j = 0; j < 4; ++j) b[j] = (short)f2bf(t[lc + j][crow]);
        *(s16x4*)(dst + (size_t)(c0 + crow) * R + r0 + lc) = b;
    }
}

// ---------------------------------------------------------------------------
// Kernel 3: pass A — hid[pair] = relu(xb[tok] @ w1t^T + b1[e]), bf16.
// 128x128 tile, single-buffered (32.5KB LDS -> 4 blocks/CU), swizzled LDS.
// Swizzle: LDS[row][chunk c] holds global chunk c^(row&7); staging lane loads
// global chunk (lane&7)^(lane>>3); reader XORs chunk with row&7.
// ---------------------------------------------------------------------------
__global__ __launch_bounds__(256, 4) void ffn1_kernel(
    const unsigned short* __restrict__ xb, const unsigned short* __restrict__ w1t,
    const float* __restrict__ b1,
    const int* __restrict__ cnt, const int* __restrict__ tok,
    const int* __restrict__ pid,
    unsigned short* __restrict__ hid, int ebase)
{
    const int le = blockIdx.z;
    const int e = ebase + le;
    const int mt = blockIdx.y;
    const int nt = blockIdx.x;
    const int Me = cnt[e];
    if (mt * BM >= Me) return;

    __shared__ unsigned short As[BM][BK];   // 16KB
    __shared__ unsigned short Bs[BN][BK];   // 16KB
    __shared__ int tl[BM];

    const int tid = threadIdx.x;
    if (tid < BM) {
        int p = mt * BM + tid;
        tl[tid] = (p < Me) ? tok[e * NTOK + p] : 0;
    }
    __syncthreads();

    const int lane = tid & 63;
    const int wv = tid >> 6;
    const int wr = wv >> 1, wc = wv & 1;

    const int srow = lane >> 3;                 // row within 8-row group
    const int scol = ((lane & 7) ^ srow) * 8;   // swizzled 16B chunk

    const unsigned short* aSrc[4];
#pragma unroll
    for (int i = 0; i < 4; ++i)
        aSrc[i] = xb + (size_t)tl[wv * 32 + i * 8 + srow] * DD + scol;
    const unsigned short* bE = w1t + (size_t)le * DD * HH;  // [H][D] local expert
    const unsigned short* bSrc[4];
#pragma unroll
    for (int i = 0; i < 4; ++i)
        bSrc[i] = bE + (size_t)(nt * BN + wv * 32 + i * 8 + srow) * DD + scol;

    f32x4 acc[4][4];
#pragma unroll
    for (int m = 0; m < 4; ++m)
#pragma unroll
        for (int n = 0; n < 4; ++n)
#pragma unroll
            for (int q = 0; q < 4; ++q) acc[m][n][q] = 0.f;

    for (int t = 0; t < DD / BK; ++t) {
        const int k0 = t * BK;
#pragma unroll
        for (int i = 0; i < 4; ++i) gload16(aSrc[i] + k0, &As[wv * 32 + i * 8][0]);
#pragma unroll
        for (int i = 0; i < 4; ++i) gload16(bSrc[i] + k0, &Bs[wv * 32 + i * 8][0]);
        __syncthreads();   // drains vmcnt(0): tile ready
#pragma unroll
        for (int ks = 0; ks < BK; ks += 32) {
            bf16x8 af[4], bfr[4];
            const int g = (ks >> 3) + (lane >> 4);
#pragma unroll
            for (int m = 0; m < 4; ++m) {
                int ar = wr * 64 + m * 16 + (lane & 15);
                af[m] = *(const bf16x8*)&As[ar][(g ^ (ar & 7)) * 8];
            }
#pragma unroll
            for (int n = 0; n < 4; ++n) {
                int br = wc * 64 + n * 16 + (lane & 15);
                bfr[n] = *(const bf16x8*)&Bs[br][(g ^ (br & 7)) * 8];
            }
#pragma unroll
            for (int m = 0; m < 4; ++m)
#pragma unroll
                for (int n = 0; n < 4; ++n)
                    acc[m][n] = __builtin_amdgcn_mfma_f32_16x16x32_bf16(af[m], bfr[n], acc[m][n], 0, 0, 0);
        }
        __syncthreads();   // all reads done before next stage overwrites
    }

    const int nbase = nt * BN;
#pragma unroll
    for (int m = 0; m < 4; ++m) {
#pragma unroll
        for (int q = 0; q < 4; ++q) {
            int rloc = wr * 64 + m * 16 + (lane >> 4) * 4 + q;
            int p = mt * BM + rloc;
            if (p < Me) {
                int pp = pid[e * NTOK + p];
                unsigned short* dst = hid + (size_t)pp * HH;
#pragma unroll
                for (int n = 0; n < 4; ++n) {
                    int ng = nbase + wc * 64 + n * 16 + (lane & 15);
                    float h = acc[m][n][q] + b1[(size_t)e * HH + ng];
                    dst[ng] = f2bf(fmaxf(h, 0.f));
                }
            }
        }
    }
}

// ---------------------------------------------------------------------------
// Kernel 4: pass B — chunks[kc][pair] = hid[pair] @ w2t[:, kc-slice]^T (bf16).
// 64x128 tile (24.8KB LDS -> 5 blocks/CU), KSPLIT=2, NO atomics.
// Wave layout 1x4: wave wv owns cols [wv*32, wv*32+32), all 64 rows.
// ---------------------------------------------------------------------------
__global__ __launch_bounds__(256, 5) void ffn2_kernel(
    const unsigned short* __restrict__ hid, const unsigned short* __restrict__ w2t,
    const int* __restrict__ cnt, const int* __restrict__ pid,
    unsigned short* __restrict__ chunks, int ebase)
{
    const int le = blockIdx.z >> 1;
    const int kc = blockIdx.z & 1;
    const int e = ebase + le;
    const int mt = blockIdx.y;
    const int nt = blockIdx.x;
    const int Me = cnt[e];
    if (mt * BM2 >= Me) return;

    __shared__ unsigned short As[BM2][BK];  // 8KB
    __shared__ unsigned short Bs[BN][BK];   // 16KB
    __shared__ int pl[BM2];

    const int tid = threadIdx.x;
    if (tid < BM2) {
        int p = mt * BM2 + tid;
        pl[tid] = (p < Me) ? pid[e * NTOK + p] : 0;
    }
    __syncthreads();

    const int lane = tid & 63;
    const int wv = tid >> 6;

    const int srow = lane >> 3;
    const int scol = ((lane & 7) ^ srow) * 8;
    const int kbase = kc * (HH / KSPLIT);

    const unsigned short* aSrc[2];
#pragma unroll
    for (int i = 0; i < 2; ++i)
        aSrc[i] = hid + (size_t)pl[wv * 16 + i * 8 + srow] * HH + kbase + scol;
    const unsigned short* bE = w2t + (size_t)le * DD * HH;  // [D][H] local expert
    const unsigned short* bSrc[4];
#pragma unroll
    for (int i = 0; i < 4; ++i)
        bSrc[i] = bE + (size_t)(nt * BN + wv * 32 + i * 8 + srow) * HH + kbase + scol;

    f32x4 acc[4][2];
#pragma unroll
    for (int m = 0; m < 4; ++m)
#pragma unroll
        for (int n = 0; n < 2; ++n)
#pragma unroll
            for (int q = 0; q < 4; ++q) acc[m][n][q] = 0.f;

    for (int t = 0; t < (HH / KSPLIT) / BK; ++t) {   // 32 k-steps
        const int k0 = t * BK;
#pragma unroll
        for (int i = 0; i < 2; ++i) gload16(aSrc[i] + k0, &As[wv * 16 + i * 8][0]);
#pragma unroll
        for (int i = 0; i < 4; ++i) gload16(bSrc[i] + k0, &Bs[wv * 32 + i * 8][0]);
        __syncthreads();
#pragma unroll
        for (int ks = 0; ks < BK; ks += 32) {
            bf16x8 af[4], bfr[2];
            const int g = (ks >> 3) + (lane >> 4);
#pragma unroll
            for (int m = 0; m < 4; ++m) {
                int ar = m * 16 + (lane & 15);
                af[m] = *(const bf16x8*)&As[ar][(g ^ (ar & 7)) * 8];
            }
#pragma unroll
            for (int n = 0; n < 2; ++n) {
                int br = wv * 32 + n * 16 + (lane & 15);
                bfr[n] = *(const bf16x8*)&Bs[br][(g ^ (br & 7)) * 8];
            }
#pragma unroll
            for (int m = 0; m < 4; ++m)
#pragma unroll
                for (int n = 0; n < 2; ++n)
                    acc[m][n] = __builtin_amdgcn_mfma_f32_16x16x32_bf16(af[m], bfr[n], acc[m][n], 0, 0, 0);
        }
        __syncthreads();
    }

    const int nbase = nt * BN;
    unsigned short* cbase = chunks + (size_t)kc * NPAIR * DD;
#pragma unroll
    for (int m = 0; m < 4; ++m) {
#pragma unroll
        for (int q = 0; q < 4; ++q) {
            int rloc = m * 16 + (lane >> 4) * 4 + q;
            int p = mt * BM2 + rloc;
            if (p < Me) {
                int pp = pl[rloc];
                unsigned short* dst = cbase + (size_t)pp * DD;
#pragma unroll
                for (int n = 0; n < 2; ++n) {
                    int ng = nbase + wv * 32 + n * 16 + (lane & 15);
                    dst[ng] = f2bf(acc[m][n][q]);
                }
            }
        }
    }
}

// ---------------------------------------------------------------------------
// Kernel 5: combine — out[t] = sum_k wtok[2t+k] * (chunk0 + chunk1 + b2[e_k]).
// One block per token; thread handles 4 consecutive d.
// ---------------------------------------------------------------------------
__global__ __launch_bounds__(256) void combine_kernel(
    const unsigned short* __restrict__ chunks, const float* __restrict__ b2,
    const int* __restrict__ etok, const float* __restrict__ wtok,
    float* __restrict__ out)
{
    const int t = blockIdx.x;
    const int d0 = threadIdx.x * 4;
    f32x4 s;
    s[0] = s[1] = s[2] = s[3] = 0.f;
#pragma unroll
    for (int k = 0; k < 2; ++k) {
        const int pair = 2 * t + k;
        const float w = wtok[pair];
        const int e = etok[pair];
        s16x4 c0 = *(const s16x4*)(chunks + (size_t)pair * DD + d0);
        s16x4 c1 = *(const s16x4*)(chunks + (size_t)(NPAIR + pair) * DD + d0);
        const float4 bb = *(const float4*)(b2 + (size_t)e * DD + d0);
        s[0] += w * (bf2f((unsigned short)c0[0]) + bf2f((unsigned short)c1[0]) + bb.x);
        s[1] += w * (bf2f((unsigned short)c0[1]) + bf2f((unsigned short)c1[1]) + bb.y);
        s[2] += w * (bf2f((unsigned short)c0[2]) + bf2f((unsigned short)c1[2]) + bb.z);
        s[3] += w * (bf2f((unsigned short)c0[3]) + bf2f((unsigned short)c1[3]) + bb.w);
    }
    *(f32x4*)(out + (size_t)t * DD + d0) = s;
}

// ---------------------------------------------------------------------------
// Workspace (bytes): cnt 256 | tok 128K | pid 128K | etok 32K | wtok 32K |
// xb 8M | hid 64M | wt 32M (4 experts at a time) | chunks 32M  => ~136.3MB
// ---------------------------------------------------------------------------
extern "C" void kernel_launch(void* const* d_in, const int* in_sizes, int n_in,
                              void* d_out, int out_size, void* d_ws, size_t ws_size,
                              hipStream_t stream) {
    const float* x   = (const float*)d_in[0];
    const float* gw  = (const float*)d_in[1];
    const float* gb  = (const float*)d_in[2];
    const float* w1  = (const float*)d_in[3];
    const float* b1  = (const float*)d_in[4];
    const float* w2  = (const float*)d_in[5];
    const float* b2  = (const float*)d_in[6];
    float* out = (float*)d_out;

    char* ws = (char*)d_ws;
    size_t off = 0;
    int*   cnt  = (int*)(ws + off);   off += 256;
    int*   tok  = (int*)(ws + off);   off += (size_t)4 * EE * NTOK;
    int*   pid  = (int*)(ws + off);   off += (size_t)4 * EE * NTOK;
    int*   etok = (int*)(ws + off);   off += (size_t)4 * NPAIR;
    float* wtok = (float*)(ws + off); off += (size_t)4 * NPAIR;
    unsigned short* xb     = (unsigned short*)(ws + off); off += (size_t)NTOK * DD * 2;
    unsigned short* hid    = (unsigned short*)(ws + off); off += (size_t)NPAIR * HH * 2;
    unsigned short* wt     = (unsigned short*)(ws + off); off += (size_t)(EE / 2) * DD * HH * 2;
    unsigned short* chunks = (unsigned short*)(ws + off); off += (size_t)KSPLIT * NPAIR * DD * 2;

    hipMemsetAsync(cnt, 0, 256, stream);

    gate_kernel<<<NTOK / 4, 256, 0, stream>>>(x, gw, gb, cnt, tok, pid, etok, wtok, xb);

    // Pass 1 in expert-halves: w1[e] [D][H] -> wt [H][D], then ffn1.
    for (int h = 0; h < 2; ++h) {
        const int e0 = h * 4;
        transpose_cvt_kernel<<<dim3(HH / 64, DD / 64, 4), 256, 0, stream>>>(
            w1 + (size_t)e0 * DD * HH, wt, DD, HH);
        ffn1_kernel<<<dim3(HH / BN, NTOK / BM, 4), 256, 0, stream>>>(
            xb, wt, b1, cnt, tok, pid, hid, e0);
    }
    // Pass 2 in expert-halves: w2[e] [H][D] -> wt [D][H], then ffn2.
    for (int h = 0; h < 2; ++h) {
        const int e0 = h * 4;
        transpose_cvt_kernel<<<dim3(DD / 64, HH / 64, 4), 256, 0, stream>>>(
            w2 + (size_t)e0 * HH * DD, wt, HH, DD);
        ffn2_kernel<<<dim3(DD / BN, NTOK / BM2, 4 * KSPLIT), 256, 0, stream>>>(
            hid, wt, cnt, pid, chunks, e0);
    }

    combine_kernel<<<NTOK, 256, 0, stream>>>(chunks, b2, etok, wtok, out);
}

// Round 8
// 557.552 us; speedup vs baseline: 1.4097x; 1.1585x over previous
//
#include <hip/hip_runtime.h>
#include <stdint.h>

// Problem constants (from reference)
#define BB 2
#define SS 2048
#define DD 1024      // model dim
#define HH 4096      // hidden dim
#define EE 8         // experts
#define NTOK (BB*SS) // 4096 tokens
#define NPAIR (NTOK*2)

// GEMM tiling: single-buffered LDS (m97 structure), high block residency.
#define BM 128       // ffn1 M-tile
#define BM2 64       // ffn2 M-tile (N only 8 tiles wide -> need more blocks)
#define BN 128
#define BK 64

typedef float f32x4 __attribute__((ext_vector_type(4)));
typedef __bf16 bf16x8 __attribute__((ext_vector_type(8)));
typedef short s16x4 __attribute__((ext_vector_type(4)));
typedef short s16x8 __attribute__((ext_vector_type(8)));

__device__ __forceinline__ unsigned short f2bf(float f) {
    union { float f; uint32_t u; } v; v.f = f;
    return (unsigned short)((v.u + 0x7FFFu + ((v.u >> 16) & 1u)) >> 16);  // RNE
}

__device__ __forceinline__ void gload16(const void* g, void* l) {
    __builtin_amdgcn_global_load_lds(
        (const __attribute__((address_space(1))) unsigned int*)g,
        (__attribute__((address_space(3))) unsigned int*)l, 16, 0, 0);
}

// ---------------------------------------------------------------------------
// Kernel 1: gating compute (f32 exact) + x -> bf16. NO global atomics
// (round-7 rocprof: 8192 same-cacheline atomicAdds serialized -> 110us).
// Writes token-major etok/wtok only; list building moved to scatter_kernel.
// ---------------------------------------------------------------------------
__global__ __launch_bounds__(256) void gate_compute(
    const float* __restrict__ x, const float* __restrict__ gw,
    const float* __restrict__ gb,
    int* __restrict__ etok, float* __restrict__ wtok,
    unsigned short* __restrict__ xb)
{
    int wave = threadIdx.x >> 6;
    int lane = threadIdx.x & 63;
    int t = blockIdx.x * 4 + wave;
    if (t >= NTOK) return;

    float acc[EE];
#pragma unroll
    for (int e = 0; e < EE; ++e) acc[e] = 0.f;

    const float* xr = x + (size_t)t * DD;
    unsigned short* xo = xb + (size_t)t * DD;
    for (int d = lane; d < DD; d += 64) {
        float xv = xr[d];
        xo[d] = f2bf(xv);
        const float* g = gw + (size_t)d * EE;
#pragma unroll
        for (int e = 0; e < EE; ++e) acc[e] += xv * g[e];
    }
#pragma unroll
    for (int e = 0; e < EE; ++e) {
#pragma unroll
        for (int off = 32; off >= 1; off >>= 1)
            acc[e] += __shfl_xor(acc[e], off);
    }
    if (lane == 0) {
        float lg[EE];
        float m = -1e30f;
#pragma unroll
        for (int e = 0; e < EE; ++e) { lg[e] = acc[e] + gb[e]; m = fmaxf(m, lg[e]); }
        float s = 0.f;
#pragma unroll
        for (int e = 0; e < EE; ++e) { lg[e] = expf(lg[e] - m); s += lg[e]; }
        float inv = 1.f / s;
        int e0 = 0; float v0 = lg[0];
#pragma unroll
        for (int e = 1; e < EE; ++e) if (lg[e] > v0) { v0 = lg[e]; e0 = e; }
        int e1 = -1; float v1 = -1.f;
#pragma unroll
        for (int e = 0; e < EE; ++e) if (e != e0 && lg[e] > v1) { v1 = lg[e]; e1 = e; }

        etok[2 * t] = e0;     wtok[2 * t] = v0 * inv;
        etok[2 * t + 1] = e1; wtok[2 * t + 1] = v1 * inv;
    }
}

// ---------------------------------------------------------------------------
// Kernel 2: scatter — build per-expert lists with LDS atomics (fast, 8 ctrs).
// Single block, 1024 threads; 8192 entries. Order within a list is irrelevant
// (pid maps back to the pair slot). Writes cnt directly (no memset needed).
// ---------------------------------------------------------------------------
__global__ __launch_bounds__(1024) void scatter_kernel(
    const int* __restrict__ etok,
    int* __restrict__ cnt, int* __restrict__ tok, int* __restrict__ pid)
{
    __shared__ int lcnt[EE];
    const int tid = threadIdx.x;
    if (tid < EE) lcnt[tid] = 0;
    __syncthreads();
    for (int p = tid; p < NPAIR; p += 1024) {
        int e = etok[p];
        int r = atomicAdd(&lcnt[e], 1);
        tok[e * NTOK + r] = p >> 1;
        pid[e * NTOK + r] = p;
    }
    __syncthreads();
    if (tid < EE) cnt[tid] = lcnt[tid];
}

// ---------------------------------------------------------------------------
// Kernel 3: tiled transpose + f32->bf16.  in [E][R][C] f32 -> out [E][C][R] bf16.
// ---------------------------------------------------------------------------
__global__ __launch_bounds__(256) void transpose_cvt_kernel(
    const float* __restrict__ in, unsigned short* __restrict__ out, int R, int C)
{
    __shared__ float t[64][65];
    const int e = blockIdx.z;
    const int r0 = blockIdx.y * 64;
    const int c0 = blockIdx.x * 64;
    const float* src = in + (size_t)e * R * C;
    unsigned short* dst = out + (size_t)e * R * C;
    const int tid = threadIdx.x;
    const int lr = tid >> 4;
    const int lc = (tid & 15) * 4;
#pragma unroll
    for (int p = 0; p < 4; ++p) {
        int row = p * 16 + lr;
        const float4 v = *(const float4*)(src + (size_t)(r0 + row) * C + c0 + lc);
        t[row][lc]     = v.x; t[row][lc + 1] = v.y;
        t[row][lc + 2] = v.z; t[row][lc + 3] = v.w;
    }
    __syncthreads();
#pragma unroll
    for (int p = 0; p < 4; ++p) {
        int crow = p * 16 + lr;
        s16x4 b;
#pragma unroll
        for (int j = 0; j < 4; ++j) b[j] = (short)f2bf(t[lc + j][crow]);
        *(s16x4*)(dst + (size_t)(c0 + crow) * R + r0 + lc) = b;
    }
}

// ---------------------------------------------------------------------------
// Kernel 4: pass A — hid[pair] = relu(xb[tok] @ w1t^T + b1[e]), bf16.
// 128x128 tile, single-buffered (32.5KB LDS -> 4 blocks/CU), swizzled LDS.
// Swizzle: LDS[row][chunk c] holds global chunk c^(row&7); staging lane loads
// global chunk (lane&7)^(lane>>3); reader XORs chunk with row&7.
// ---------------------------------------------------------------------------
__global__ __launch_bounds__(256, 4) void ffn1_kernel(
    const unsigned short* __restrict__ xb, const unsigned short* __restrict__ w1t,
    const float* __restrict__ b1,
    const int* __restrict__ cnt, const int* __restrict__ tok,
    const int* __restrict__ pid,
    unsigned short* __restrict__ hid)
{
    const int e = blockIdx.z;
    const int mt = blockIdx.y;
    const int nt = blockIdx.x;
    const int Me = cnt[e];
    if (mt * BM >= Me) return;

    __shared__ unsigned short As[BM][BK];   // 16KB
    __shared__ unsigned short Bs[BN][BK];   // 16KB
    __shared__ int tl[BM];

    const int tid = threadIdx.x;
    if (tid < BM) {
        int p = mt * BM + tid;
        tl[tid] = (p < Me) ? tok[e * NTOK + p] : 0;
    }
    __syncthreads();

    const int lane = tid & 63;
    const int wv = tid >> 6;
    const int wr = wv >> 1, wc = wv & 1;

    const int srow = lane >> 3;                 // row within 8-row group
    const int scol = ((lane & 7) ^ srow) * 8;   // swizzled 16B chunk

    const unsigned short* aSrc[4];
#pragma unroll
    for (int i = 0; i < 4; ++i)
        aSrc[i] = xb + (size_t)tl[wv * 32 + i * 8 + srow] * DD + scol;
    const unsigned short* bE = w1t + (size_t)e * DD * HH;  // [H][D]
    const unsigned short* bSrc[4];
#pragma unroll
    for (int i = 0; i < 4; ++i)
        bSrc[i] = bE + (size_t)(nt * BN + wv * 32 + i * 8 + srow) * DD + scol;

    f32x4 acc[4][4];
#pragma unroll
    for (int m = 0; m < 4; ++m)
#pragma unroll
        for (int n = 0; n < 4; ++n)
#pragma unroll
            for (int q = 0; q < 4; ++q) acc[m][n][q] = 0.f;

    for (int t = 0; t < DD / BK; ++t) {
        const int k0 = t * BK;
#pragma unroll
        for (int i = 0; i < 4; ++i) gload16(aSrc[i] + k0, &As[wv * 32 + i * 8][0]);
#pragma unroll
        for (int i = 0; i < 4; ++i) gload16(bSrc[i] + k0, &Bs[wv * 32 + i * 8][0]);
        __syncthreads();   // drains vmcnt(0): tile ready
#pragma unroll
        for (int ks = 0; ks < BK; ks += 32) {
            bf16x8 af[4], bfr[4];
            const int g = (ks >> 3) + (lane >> 4);
#pragma unroll
            for (int m = 0; m < 4; ++m) {
                int ar = wr * 64 + m * 16 + (lane & 15);
                af[m] = *(const bf16x8*)&As[ar][(g ^ (ar & 7)) * 8];
            }
#pragma unroll
            for (int n = 0; n < 4; ++n) {
                int br = wc * 64 + n * 16 + (lane & 15);
                bfr[n] = *(const bf16x8*)&Bs[br][(g ^ (br & 7)) * 8];
            }
#pragma unroll
            for (int m = 0; m < 4; ++m)
#pragma unroll
                for (int n = 0; n < 4; ++n)
                    acc[m][n] = __builtin_amdgcn_mfma_f32_16x16x32_bf16(af[m], bfr[n], acc[m][n], 0, 0, 0);
        }
        __syncthreads();   // all reads done before next stage overwrites
    }

    const int nbase = nt * BN;
#pragma unroll
    for (int m = 0; m < 4; ++m) {
#pragma unroll
        for (int q = 0; q < 4; ++q) {
            int rloc = wr * 64 + m * 16 + (lane >> 4) * 4 + q;
            int p = mt * BM + rloc;
            if (p < Me) {
                int pp = pid[e * NTOK + p];
                unsigned short* dst = hid + (size_t)pp * HH;
#pragma unroll
                for (int n = 0; n < 4; ++n) {
                    int ng = nbase + wc * 64 + n * 16 + (lane & 15);
                    float h = acc[m][n][q] + b1[(size_t)e * HH + ng];
                    dst[ng] = f2bf(fmaxf(h, 0.f));
                }
            }
        }
    }
}

// ---------------------------------------------------------------------------
// Kernel 5: pass B — out[t] += wtok[pair] * (hid[pair] @ w2t^T + b2[e]).
// Full K=4096 per block (no split-K), fused weighted epilogue with f32
// atomicAdd (each out element receives exactly 2 adds -> no contention).
// 64x128 tile (24.8KB LDS -> 5 blocks/CU). Wave wv owns cols [wv*32, +32).
// ---------------------------------------------------------------------------
__global__ __launch_bounds__(256, 5) void ffn2_kernel(
    const unsigned short* __restrict__ hid, const unsigned short* __restrict__ w2t,
    const float* __restrict__ b2,
    const int* __restrict__ cnt, const int* __restrict__ pid,
    const float* __restrict__ wtok,
    float* __restrict__ out)
{
    const int e = blockIdx.z;
    const int mt = blockIdx.y;
    const int nt = blockIdx.x;
    const int Me = cnt[e];
    if (mt * BM2 >= Me) return;

    __shared__ unsigned short As[BM2][BK];  // 8KB
    __shared__ unsigned short Bs[BN][BK];   // 16KB
    __shared__ int pl[BM2];

    const int tid = threadIdx.x;
    if (tid < BM2) {
        int p = mt * BM2 + tid;
        pl[tid] = (p < Me) ? pid[e * NTOK + p] : 0;
    }
    __syncthreads();

    const int lane = tid & 63;
    const int wv = tid >> 6;

    const int srow = lane >> 3;
    const int scol = ((lane & 7) ^ srow) * 8;

    const unsigned short* aSrc[2];
#pragma unroll
    for (int i = 0; i < 2; ++i)
        aSrc[i] = hid + (size_t)pl[wv * 16 + i * 8 + srow] * HH + scol;
    const unsigned short* bE = w2t + (size_t)e * DD * HH;  // [D][H]
    const unsigned short* bSrc[4];
#pragma unroll
    for (int i = 0; i < 4; ++i)
        bSrc[i] = bE + (size_t)(nt * BN + wv * 32 + i * 8 + srow) * HH + scol;

    f32x4 acc[4][2];
#pragma unroll
    for (int m = 0; m < 4; ++m)
#pragma unroll
        for (int n = 0; n < 2; ++n)
#pragma unroll
            for (int q = 0; q < 4; ++q) acc[m][n][q] = 0.f;

    for (int t = 0; t < HH / BK; ++t) {   // 64 k-steps
        const int k0 = t * BK;
#pragma unroll
        for (int i = 0; i < 2; ++i) gload16(aSrc[i] + k0, &As[wv * 16 + i * 8][0]);
#pragma unroll
        for (int i = 0; i < 4; ++i) gload16(bSrc[i] + k0, &Bs[wv * 32 + i * 8][0]);
        __syncthreads();
#pragma unroll
        for (int ks = 0; ks < BK; ks += 32) {
            bf16x8 af[4], bfr[2];
            const int g = (ks >> 3) + (lane >> 4);
#pragma unroll
            for (int m = 0; m < 4; ++m) {
                int ar = m * 16 + (lane & 15);
                af[m] = *(const bf16x8*)&As[ar][(g ^ (ar & 7)) * 8];
            }
#pragma unroll
            for (int n = 0; n < 2; ++n) {
                int br = wv * 32 + n * 16 + (lane & 15);
                bfr[n] = *(const bf16x8*)&Bs[br][(g ^ (br & 7)) * 8];
            }
#pragma unroll
            for (int m = 0; m < 4; ++m)
#pragma unroll
                for (int n = 0; n < 2; ++n)
                    acc[m][n] = __builtin_amdgcn_mfma_f32_16x16x32_bf16(af[m], bfr[n], acc[m][n], 0, 0, 0);
        }
        __syncthreads();
    }

    const int nbase = nt * BN;
#pragma unroll
    for (int m = 0; m < 4; ++m) {
#pragma unroll
        for (int q = 0; q < 4; ++q) {
            int rloc = m * 16 + (lane >> 4) * 4 + q;
            int p = mt * BM2 + rloc;
            if (p < Me) {
                int pp = pl[rloc];
                int t = pp >> 1;
                float wvv = wtok[pp];
                float* dst = out + (size_t)t * DD;
#pragma unroll
                for (int n = 0; n < 2; ++n) {
                    int ng = nbase + wv * 32 + n * 16 + (lane & 15);
                    atomicAdd(&dst[ng], wvv * (acc[m][n][q] + b2[(size_t)e * DD + ng]));
                }
            }
        }
    }
}

// ---------------------------------------------------------------------------
// Workspace (bytes): cnt 256 | tok 128K | pid 128K | etok 32K | wtok 32K |
// xb 8M | hid 64M | wt 64M (w1t, then reused for w2t; stream-ordered)
// Total ~136.3 MiB (within the proven 136.8 MiB envelope).
// ---------------------------------------------------------------------------
extern "C" void kernel_launch(void* const* d_in, const int* in_sizes, int n_in,
                              void* d_out, int out_size, void* d_ws, size_t ws_size,
                              hipStream_t stream) {
    const float* x   = (const float*)d_in[0];
    const float* gw  = (const float*)d_in[1];
    const float* gb  = (const float*)d_in[2];
    const float* w1  = (const float*)d_in[3];
    const float* b1  = (const float*)d_in[4];
    const float* w2  = (const float*)d_in[5];
    const float* b2  = (const float*)d_in[6];
    float* out = (float*)d_out;

    char* ws = (char*)d_ws;
    size_t off = 0;
    int*   cnt  = (int*)(ws + off);   off += 256;
    int*   tok  = (int*)(ws + off);   off += (size_t)4 * EE * NTOK;
    int*   pid  = (int*)(ws + off);   off += (size_t)4 * EE * NTOK;
    int*   etok = (int*)(ws + off);   off += (size_t)4 * NPAIR;
    float* wtok = (float*)(ws + off); off += (size_t)4 * NPAIR;
    unsigned short* xb  = (unsigned short*)(ws + off); off += (size_t)NTOK * DD * 2;
    unsigned short* hid = (unsigned short*)(ws + off); off += (size_t)NPAIR * HH * 2;
    unsigned short* wt  = (unsigned short*)(ws + off); off += (size_t)EE * DD * HH * 2;

    hipMemsetAsync(out, 0, (size_t)out_size * sizeof(float), stream);

    gate_compute<<<NTOK / 4, 256, 0, stream>>>(x, gw, gb, etok, wtok, xb);
    scatter_kernel<<<1, 1024, 0, stream>>>(etok, cnt, tok, pid);

    // w1 [E][D][H] -> wt = w1t [E][H][D], then ffn1 over all 8 experts.
    transpose_cvt_kernel<<<dim3(HH / 64, DD / 64, EE), 256, 0, stream>>>(w1, wt, DD, HH);
    ffn1_kernel<<<dim3(HH / BN, NTOK / BM, EE), 256, 0, stream>>>(
        xb, wt, b1, cnt, tok, pid, hid);

    // w2 [E][H][D] -> wt = w2t [E][D][H] (reuse buffer; stream-ordered), ffn2.
    transpose_cvt_kernel<<<dim3(DD / 64, HH / 64, EE), 256, 0, stream>>>(w2, wt, HH, DD);
    ffn2_kernel<<<dim3(DD / BN, NTOK / BM2, EE), 256, 0, stream>>>(
        hid, wt, b2, cnt, pid, wtok, out);
}